// Round 4
// baseline (1784.222 us; speedup 1.0000x reference)
//
#include <hip/hip_runtime.h>
#include <cmath>
#include <vector>
#include <thread>
#include <algorithm>
#include <cstring>

// ---------------------------------------------------------------------------
// Problem constants: x (B=256, D=768, L=128) f32. THETA=128, BN_EPS=1e-5.
// Pipeline (after algebraic folding):
//   u[b,l]   = relu(sum_d x[b,d,l]*Wu[d] + bu)
//   G        = W_h[:, :D] @ H                   (H: host-computed, const)
//   h[b,o,l] = relu( sum_{k<=l} G[o,k]*u[b,l-k]
//                    + sum_d W_h[o,D+d]*x[b,d,l] + bh[o] )
//   out[b,o,l] = s[o]*(sum_d cw[o,d]*h[b,d,l]) + c2[o]
//     where s = gamma/sqrt(var+eps), c2 = (conv_b-mean)*s+beta  (BN folded,
//     applied in epilogue -> no materialized Cw2, ws stays under 1 MB)
// ---------------------------------------------------------------------------

#define DD 768
#define LL 128
#define BB 256

// ============================ host-side H ==================================
namespace lmu_host {

constexpr int MD = DD;
constexpr int NN = MD + 1;  // 769 (augmented)

static float Hmat[MD * LL];      // H[d*L + t]  (fallback, pageable)
static float* Hpinned = nullptr; // pinned copy if hipHostMalloc succeeds

static void mm(const double* A, const double* B, double* C, int n) {
  unsigned T = std::thread::hardware_concurrency();
  if (T == 0) T = 4;
  if (T > 32) T = 32;
  int chunk = (n + (int)T - 1) / (int)T;
  std::vector<std::thread> th;
  for (unsigned ti = 0; ti < T; ++ti) {
    int r0 = (int)ti * chunk, r1 = std::min(n, r0 + chunk);
    if (r0 >= r1) break;
    th.emplace_back([=]() {
      for (int i = r0; i < r1; ++i) {
        double* Ci = C + (size_t)i * n;
        for (int j = 0; j < n; ++j) Ci[j] = 0.0;
        for (int k = 0; k < n; ++k) {
          double a = A[(size_t)i * n + k];
          const double* Bk = B + (size_t)k * n;
          for (int j = 0; j < n; ++j) Ci[j] += a * Bk[j];
        }
      }
    });
  }
  for (auto& t : th) t.join();
}

// Solve A X = B, X overwrites B. Gaussian elimination w/ partial pivoting.
static void solveMat(std::vector<double>& A, std::vector<double>& B, int n) {
  for (int k = 0; k < n; ++k) {
    int p = k;
    double mx = std::fabs(A[(size_t)k * n + k]);
    for (int i = k + 1; i < n; ++i) {
      double v = std::fabs(A[(size_t)i * n + k]);
      if (v > mx) { mx = v; p = i; }
    }
    if (p != k) {
      for (int j = 0; j < n; ++j) std::swap(A[(size_t)k * n + j], A[(size_t)p * n + j]);
      for (int j = 0; j < n; ++j) std::swap(B[(size_t)k * n + j], B[(size_t)p * n + j]);
    }
    double inv = 1.0 / A[(size_t)k * n + k];
    for (int i = k + 1; i < n; ++i) {
      double f = A[(size_t)i * n + k] * inv;
      if (f == 0.0) continue;
      A[(size_t)i * n + k] = 0.0;
      double* Ai = &A[(size_t)i * n];
      const double* Ak = &A[(size_t)k * n];
      for (int j = k + 1; j < n; ++j) Ai[j] -= f * Ak[j];
      double* Bi = &B[(size_t)i * n];
      const double* Bk = &B[(size_t)k * n];
      for (int j = 0; j < n; ++j) Bi[j] -= f * Bk[j];
    }
  }
  for (int k = n - 1; k >= 0; --k) {
    double inv = 1.0 / A[(size_t)k * n + k];
    double* Bk = &B[(size_t)k * n];
    for (int j = 0; j < n; ++j) Bk[j] *= inv;
    for (int i = 0; i < k; ++i) {
      double f = A[(size_t)i * n + k];
      if (f == 0.0) continue;
      double* Bi = &B[(size_t)i * n];
      for (int j = 0; j < n; ++j) Bi[j] -= f * Bk[j];
    }
  }
}

struct HInit {
  HInit() {
    const int n = NN;
    const size_t n2 = (size_t)n * n;
    std::vector<double> M(n2, 0.0);
    for (int i = 0; i < MD; ++i) {
      double R = (2.0 * i + 1.0) / 128.0;  // THETA = 128
      for (int j = 0; j < MD; ++j) {
        double v = (i < j) ? -1.0 : (((i - j + 1) & 1) ? -1.0 : 1.0);
        M[(size_t)i * n + j] = v * R;
      }
      M[(size_t)i * n + MD] = ((i & 1) ? -1.0 : 1.0) * R;  // B column
    }
    // expm via Pade-13 scaling & squaring in float64.
    double nrm = 0.0;
    for (int j = 0; j < n; ++j) {
      double s = 0;
      for (int i = 0; i < n; ++i) s += std::fabs(M[(size_t)i * n + j]);
      if (s > nrm) nrm = s;
    }
    int ssq = 0;
    const double theta = 5.371920351148152;
    if (nrm > theta) ssq = (int)std::ceil(std::log2(nrm / theta));
    const double sc = std::ldexp(1.0, -ssq);
    for (size_t i = 0; i < n2; ++i) M[i] *= sc;

    std::vector<double> A2(n2), A4(n2), A6(n2), T1(n2), T2(n2), U(n2), P(n2), Q(n2);
    mm(M.data(), M.data(), A2.data(), n);
    mm(A2.data(), A2.data(), A4.data(), n);
    mm(A2.data(), A4.data(), A6.data(), n);
    const double b[14] = {64764752532480000.0, 32382376266240000.0, 7771770303897600.0,
                          1187353796428800.0,  129060195264000.0,   10559470521600.0,
                          670442572800.0,      33522128640.0,       1323241920.0,
                          40840800.0,          960960.0,            16380.0,
                          182.0,               1.0};
    for (size_t i = 0; i < n2; ++i) T2[i] = b[13] * A6[i] + b[11] * A4[i] + b[9] * A2[i];
    mm(A6.data(), T2.data(), T1.data(), n);
    for (size_t i = 0; i < n2; ++i) T1[i] += b[7] * A6[i] + b[5] * A4[i] + b[3] * A2[i];
    for (int i = 0; i < n; ++i) T1[(size_t)i * n + i] += b[1];
    mm(M.data(), T1.data(), U.data(), n);
    for (size_t i = 0; i < n2; ++i) T2[i] = b[12] * A6[i] + b[10] * A4[i] + b[8] * A2[i];
    mm(A6.data(), T2.data(), T1.data(), n);
    for (size_t i = 0; i < n2; ++i) T1[i] += b[6] * A6[i] + b[4] * A4[i] + b[2] * A2[i];
    for (int i = 0; i < n; ++i) T1[(size_t)i * n + i] += b[0];
    for (size_t i = 0; i < n2; ++i) { P[i] = T1[i] + U[i]; Q[i] = T1[i] - U[i]; }
    solveMat(Q, P, n);  // P = expm(M/2^ssq)
    for (int r = 0; r < ssq; ++r) { mm(P.data(), P.data(), T1.data(), n); P.swap(T1); }

    // scan: H[:, t] = Ad^t Bd  ->  matvec recursion (f64, cast at the end)
    std::vector<double> h(MD), hn(MD);
    for (int i = 0; i < MD; ++i) {
      h[i] = P[(size_t)i * n + MD];
      Hmat[i * LL + 0] = (float)h[i];
    }
    for (int t = 1; t < LL; ++t) {
      for (int i = 0; i < MD; ++i) {
        const double* Pi = &P[(size_t)i * n];
        double a = 0;
        for (int k = 0; k < MD; ++k) a += Pi[k] * h[k];
        hn[i] = a;
      }
      for (int i = 0; i < MD; ++i) {
        h[i] = hn[i];
        Hmat[i * LL + t] = (float)hn[i];
      }
    }

    // Pinned staging buffer: hipMemcpyAsync H2D from pinned memory is
    // graph-capture-safe. Allocated once at dlopen (outside capture).
    float* p = nullptr;
    if (hipHostMalloc((void**)&p, sizeof(Hmat), hipHostMallocDefault) == hipSuccess
        && p != nullptr) {
      std::memcpy(p, Hmat, sizeof(Hmat));
      Hpinned = p;
    }
  }
};
static HInit g_hinit;  // runs once at dlopen; graph replays never pay for it

}  // namespace lmu_host

// ============================ device kernels ===============================

// u[b,l] = relu(sum_d x[b,d,l]*Wu[d] + bu)
__global__ void k_u(const float* __restrict__ x, const float* __restrict__ Wu,
                    const float* __restrict__ bu, float* __restrict__ u) {
  int b = blockIdx.x;
  int t = threadIdx.x;         // 256
  int l4 = t & 31;             // 32 float4 groups over l
  int dg = t >> 5;             // 8 d-groups
  const float* xb = x + (size_t)b * DD * LL;
  float4 acc = {0.f, 0.f, 0.f, 0.f};
  for (int d = dg; d < DD; d += 8) {
    float w = Wu[d];
    float4 xv = *reinterpret_cast<const float4*>(xb + (size_t)d * LL + l4 * 4);
    acc.x += w * xv.x; acc.y += w * xv.y; acc.z += w * xv.z; acc.w += w * xv.w;
  }
  __shared__ float4 red[256];
  red[t] = acc;
  __syncthreads();
  if (t < 32) {
    float4 s = red[t];
    for (int g = 1; g < 8; ++g) {
      float4 o = red[g * 32 + t];
      s.x += o.x; s.y += o.y; s.z += o.z; s.w += o.w;
    }
    float bb = bu[0];
    float* up = u + (size_t)b * LL + t * 4;
    up[0] = fmaxf(s.x + bb, 0.f);
    up[1] = fmaxf(s.y + bb, 0.f);
    up[2] = fmaxf(s.z + bb, 0.f);
    up[3] = fmaxf(s.w + bb, 0.f);
  }
}

// G[o,t] = sum_d W_h[o, d] * H[d, t]   (K=768, out 768x128)
__global__ void k_G(const float* __restrict__ Wh, const float* __restrict__ Hm,
                    float* __restrict__ G) {
  int o = blockIdx.x;
  int t = threadIdx.x;  // 128
  const float* wr = Wh + (size_t)o * (2 * DD);
  float a0 = 0.f, a1 = 0.f, a2 = 0.f, a3 = 0.f;
  for (int d = 0; d < DD; d += 4) {
    a0 += wr[d + 0] * Hm[(size_t)(d + 0) * LL + t];
    a1 += wr[d + 1] * Hm[(size_t)(d + 1) * LL + t];
    a2 += wr[d + 2] * Hm[(size_t)(d + 2) * LL + t];
    a3 += wr[d + 3] * Hm[(size_t)(d + 3) * LL + t];
  }
  G[(size_t)o * LL + t] = (a0 + a1) + (a2 + a3);
}

__device__ __forceinline__ void mac16x3(float (&acc)[3][16], const float* __restrict__ br,
                                        float a0, float a1, float a2) {
  float4 q0 = *(const float4*)(br + 0);
  float4 q1 = *(const float4*)(br + 4);
  float4 q2 = *(const float4*)(br + 8);
  float4 q3 = *(const float4*)(br + 12);
  float bv[16] = {q0.x, q0.y, q0.z, q0.w, q1.x, q1.y, q1.z, q1.w,
                  q2.x, q2.y, q2.z, q2.w, q3.x, q3.y, q3.z, q3.w};
#pragma unroll
  for (int l = 0; l < 16; ++l) {
    acc[0][l] = fmaf(a0, bv[l], acc[0][l]);
    acc[1][l] = fmaf(a1, bv[l], acc[1][l]);
    acc[2][l] = fmaf(a2, bv[l], acc[2][l]);
  }
}

// Fused: h_tile (768 x 16) in LDS, then out_tile = s*(cw @ relu(h)) + c2.
// grid: (8 l-tiles, 256 batches); block: 256 threads (4 waves).
// Wave w owns output rows {w*192 + j*64 + lane : j=0..2}.
// LDS ~61 KB -> 2 blocks/CU (8 waves/CU, 2/SIMD); unroll 2 on the k-loops
// doubles load->use distance so the compiler can pipeline the A-operand
// float4 loads across iterations (thin-occupancy latency insurance).
__global__ __launch_bounds__(256, 2) void k_main(
    const float* __restrict__ x, const float* __restrict__ Wh,
    const float* __restrict__ bh, const float* __restrict__ u,
    const float* __restrict__ G, const float* __restrict__ cw,
    const float* __restrict__ cb, const float* __restrict__ gam,
    const float* __restrict__ bet, const float* __restrict__ mu,
    const float* __restrict__ var, float* __restrict__ out) {
  const int lt = blockIdx.x;   // 0..7  (16 l's each)
  const int b = blockIdx.y;    // 0..255
  const int t = threadIdx.x;
  const int w = t >> 6, lane = t & 63;
  const int l0 = lt * 16;
  const int r0 = w * 192 + lane;

  __shared__ float u_s[LL];
  __shared__ float T_s[LL][16];   // Toeplitz tile: T[k][l] = u[l0+l-k] (l0+l>=k)
  __shared__ float h_s[DD][16];   // 48 KiB
  __shared__ float Bs[64][16];    // x K-chunk staging

  if (t < LL) u_s[t] = u[(size_t)b * LL + t];
  __syncthreads();
  for (int i = t; i < LL * 16; i += 256) {
    int k = i >> 4, l = i & 15;
    int lg = l0 + l;
    T_s[k][l] = (lg >= k) ? u_s[lg - k] : 0.f;
  }
  __syncthreads();

  // ---- phase 1: h = relu(G @ T + Wh2 @ x + bh) ----
  float acc[3][16];
#pragma unroll
  for (int j = 0; j < 3; ++j) {
    float bb = bh[r0 + j * 64];
#pragma unroll
    for (int l = 0; l < 16; ++l) acc[j][l] = bb;
  }

  {  // conv part: K = 128 over (G, T_s)
    const float* G0 = G + (size_t)(r0) * LL;
    const float* G1 = G + (size_t)(r0 + 64) * LL;
    const float* G2 = G + (size_t)(r0 + 128) * LL;
#pragma unroll 2
    for (int k = 0; k < LL; k += 4) {
      float4 a0 = *(const float4*)(G0 + k);
      float4 a1 = *(const float4*)(G1 + k);
      float4 a2 = *(const float4*)(G2 + k);
      mac16x3(acc, &T_s[k + 0][0], a0.x, a1.x, a2.x);
      mac16x3(acc, &T_s[k + 1][0], a0.y, a1.y, a2.y);
      mac16x3(acc, &T_s[k + 2][0], a0.z, a1.z, a2.z);
      mac16x3(acc, &T_s[k + 3][0], a0.w, a1.w, a2.w);
    }
  }

  {  // x part: K = 768 over (Wh2, x) in chunks of 64 staged to LDS
    const float* W0 = Wh + (size_t)(r0) * (2 * DD) + DD;
    const float* W1 = Wh + (size_t)(r0 + 64) * (2 * DD) + DD;
    const float* W2 = Wh + (size_t)(r0 + 128) * (2 * DD) + DD;
    const float* xb = x + (size_t)b * DD * LL + l0;
    const int kk = t >> 2, l4 = t & 3;
#pragma unroll 1
    for (int kc = 0; kc < 12; ++kc) {
      *(float4*)&Bs[kk][l4 * 4] =
          *(const float4*)(xb + (size_t)(kc * 64 + kk) * LL + l4 * 4);
      __syncthreads();
      const int kb = kc * 64;
#pragma unroll 2
      for (int k = 0; k < 64; k += 4) {
        float4 a0 = *(const float4*)(W0 + kb + k);
        float4 a1 = *(const float4*)(W1 + kb + k);
        float4 a2 = *(const float4*)(W2 + kb + k);
        mac16x3(acc, &Bs[k + 0][0], a0.x, a1.x, a2.x);
        mac16x3(acc, &Bs[k + 1][0], a0.y, a1.y, a2.y);
        mac16x3(acc, &Bs[k + 2][0], a0.z, a1.z, a2.z);
        mac16x3(acc, &Bs[k + 3][0], a0.w, a1.w, a2.w);
      }
      __syncthreads();
    }
  }

#pragma unroll
  for (int j = 0; j < 3; ++j) {
    int r = r0 + j * 64;
#pragma unroll
    for (int l = 0; l < 16; ++l) h_s[r][l] = fmaxf(acc[j][l], 0.f);
  }
  __syncthreads();

  // ---- phase 2: out = s*(cw @ h) + c2  (BN folded in epilogue) ----
  float acc2[3][16];
#pragma unroll
  for (int j = 0; j < 3; ++j) {
#pragma unroll
    for (int l = 0; l < 16; ++l) acc2[j][l] = 0.f;
  }
  {
    const float* C0 = cw + (size_t)(r0) * DD;
    const float* C1 = cw + (size_t)(r0 + 64) * DD;
    const float* C2 = cw + (size_t)(r0 + 128) * DD;
#pragma unroll 2
    for (int k = 0; k < DD; k += 4) {
      float4 a0 = *(const float4*)(C0 + k);
      float4 a1 = *(const float4*)(C1 + k);
      float4 a2 = *(const float4*)(C2 + k);
      mac16x3(acc2, &h_s[k + 0][0], a0.x, a1.x, a2.x);
      mac16x3(acc2, &h_s[k + 1][0], a0.y, a1.y, a2.y);
      mac16x3(acc2, &h_s[k + 2][0], a0.z, a1.z, a2.z);
      mac16x3(acc2, &h_s[k + 3][0], a0.w, a1.w, a2.w);
    }
  }

  float* ob = out + (size_t)b * DD * LL + l0;
#pragma unroll
  for (int j = 0; j < 3; ++j) {
    int r = r0 + j * 64;
    float sc = gam[r] * rsqrtf(var[r] + 1e-5f);
    float c2 = (cb[r] - mu[r]) * sc + bet[r];
#pragma unroll
    for (int l4 = 0; l4 < 4; ++l4) {
      *(float4*)(ob + (size_t)r * LL + l4 * 4) =
          make_float4(fmaf(sc, acc2[j][l4 * 4 + 0], c2),
                      fmaf(sc, acc2[j][l4 * 4 + 1], c2),
                      fmaf(sc, acc2[j][l4 * 4 + 2], c2),
                      fmaf(sc, acc2[j][l4 * 4 + 3], c2));
    }
  }
}

// ============================ launch =======================================

extern "C" void kernel_launch(void* const* d_in, const int* in_sizes, int n_in,
                              void* d_out, int out_size, void* d_ws, size_t ws_size,
                              hipStream_t stream) {
  const float* x   = (const float*)d_in[0];
  const float* Wu  = (const float*)d_in[1];
  const float* bu  = (const float*)d_in[2];
  const float* Wh  = (const float*)d_in[3];
  const float* bh  = (const float*)d_in[4];
  const float* cw  = (const float*)d_in[5];
  const float* cb  = (const float*)d_in[6];
  const float* gam = (const float*)d_in[7];
  const float* bet = (const float*)d_in[8];
  const float* mu  = (const float*)d_in[9];
  const float* var = (const float*)d_in[10];
  float* out = (float*)d_out;

  float* ws = (float*)d_ws;
  float* H_d = ws;             // 768*128 = 98304 floats
  float* u_d = ws + 98304;     // 256*128 = 32768
  float* G_d = ws + 131072;    // 768*128 = 98304  -> total 917504 B (<1 MB)

  const float* Hsrc = lmu_host::Hpinned ? lmu_host::Hpinned : lmu_host::Hmat;
  hipMemcpyAsync(H_d, Hsrc, sizeof(lmu_host::Hmat), hipMemcpyHostToDevice, stream);

  hipLaunchKernelGGL(k_u, dim3(256), dim3(256), 0, stream, x, Wu, bu, u_d);
  hipLaunchKernelGGL(k_G, dim3(768), dim3(128), 0, stream, Wh, H_d, G_d);
  hipLaunchKernelGGL(k_main, dim3(8, 256), dim3(256), 0, stream,
                     x, Wh, bh, u_d, G_d, cw, cb, gam, bet, mu, var, out);
}

// Round 5
// 568.091 us; speedup vs baseline: 3.1407x; 3.1407x over previous
//
#include <hip/hip_runtime.h>
#include <cmath>
#include <vector>
#include <thread>
#include <algorithm>
#include <cstring>

// ---------------------------------------------------------------------------
// LMU fused pipeline, MFMA split-bf16 edition.
//   u[b,l]   = relu(sum_d x[b,d,l]*Wu[d] + bu)                    (k_u, f32)
//   G        = W_h[:, :D] @ H      (H host-computed f64 expm)     (k_G, f32)
//   A1       = [W_h[:, D:] | G]  -> bf16 hi/lo split              (k_splitA1)
//   S1: h[b] = relu(A1 @ [x_b ; T_b] + bh)   K=896   (k_gemm<0>, MFMA)
//   S2: out  = sc*(cw @ h_b) + c2            K=768   (k_gemm<1>, MFMA)
// Split-bf16: v = hi + lo, products hh + hl + lh (ll dropped), err ~2^-17.
// ---------------------------------------------------------------------------

#define DD 768
#define LL 128
#define BB 256

using u16 = unsigned short;
using u32 = unsigned int;
using f32x4 = __attribute__((ext_vector_type(4))) float;
using short8 = __attribute__((ext_vector_type(8))) short;

// ============================ host-side H ==================================
namespace lmu_host {

constexpr int MD = DD;
constexpr int NN = MD + 1;  // 769 (augmented)

static float Hmat[MD * LL];      // H[d*L + t]
static float* Hpinned = nullptr;

static void mm(const double* A, const double* B, double* C, int n) {
  unsigned T = std::thread::hardware_concurrency();
  if (T == 0) T = 4;
  if (T > 32) T = 32;
  int chunk = (n + (int)T - 1) / (int)T;
  std::vector<std::thread> th;
  for (unsigned ti = 0; ti < T; ++ti) {
    int r0 = (int)ti * chunk, r1 = std::min(n, r0 + chunk);
    if (r0 >= r1) break;
    th.emplace_back([=]() {
      for (int i = r0; i < r1; ++i) {
        double* Ci = C + (size_t)i * n;
        for (int j = 0; j < n; ++j) Ci[j] = 0.0;
        for (int k = 0; k < n; ++k) {
          double a = A[(size_t)i * n + k];
          const double* Bk = B + (size_t)k * n;
          for (int j = 0; j < n; ++j) Ci[j] += a * Bk[j];
        }
      }
    });
  }
  for (auto& t : th) t.join();
}

static void solveMat(std::vector<double>& A, std::vector<double>& B, int n) {
  for (int k = 0; k < n; ++k) {
    int p = k;
    double mx = std::fabs(A[(size_t)k * n + k]);
    for (int i = k + 1; i < n; ++i) {
      double v = std::fabs(A[(size_t)i * n + k]);
      if (v > mx) { mx = v; p = i; }
    }
    if (p != k) {
      for (int j = 0; j < n; ++j) std::swap(A[(size_t)k * n + j], A[(size_t)p * n + j]);
      for (int j = 0; j < n; ++j) std::swap(B[(size_t)k * n + j], B[(size_t)p * n + j]);
    }
    double inv = 1.0 / A[(size_t)k * n + k];
    for (int i = k + 1; i < n; ++i) {
      double f = A[(size_t)i * n + k] * inv;
      if (f == 0.0) continue;
      A[(size_t)i * n + k] = 0.0;
      double* Ai = &A[(size_t)i * n];
      const double* Ak = &A[(size_t)k * n];
      for (int j = k + 1; j < n; ++j) Ai[j] -= f * Ak[j];
      double* Bi = &B[(size_t)i * n];
      const double* Bk = &B[(size_t)k * n];
      for (int j = 0; j < n; ++j) Bi[j] -= f * Bk[j];
    }
  }
  for (int k = n - 1; k >= 0; --k) {
    double inv = 1.0 / A[(size_t)k * n + k];
    double* Bk = &B[(size_t)k * n];
    for (int j = 0; j < n; ++j) Bk[j] *= inv;
    for (int i = 0; i < k; ++i) {
      double f = A[(size_t)i * n + k];
      if (f == 0.0) continue;
      double* Bi = &B[(size_t)i * n];
      for (int j = 0; j < n; ++j) Bi[j] -= f * Bk[j];
    }
  }
}

struct HInit {
  HInit() {
    const int n = NN;
    const size_t n2 = (size_t)n * n;
    std::vector<double> M(n2, 0.0);
    for (int i = 0; i < MD; ++i) {
      double R = (2.0 * i + 1.0) / 128.0;  // THETA = 128
      for (int j = 0; j < MD; ++j) {
        double v = (i < j) ? -1.0 : (((i - j + 1) & 1) ? -1.0 : 1.0);
        M[(size_t)i * n + j] = v * R;
      }
      M[(size_t)i * n + MD] = ((i & 1) ? -1.0 : 1.0) * R;
    }
    double nrm = 0.0;
    for (int j = 0; j < n; ++j) {
      double s = 0;
      for (int i = 0; i < n; ++i) s += std::fabs(M[(size_t)i * n + j]);
      if (s > nrm) nrm = s;
    }
    int ssq = 0;
    const double theta = 5.371920351148152;
    if (nrm > theta) ssq = (int)std::ceil(std::log2(nrm / theta));
    const double sc = std::ldexp(1.0, -ssq);
    for (size_t i = 0; i < n2; ++i) M[i] *= sc;

    std::vector<double> A2(n2), A4(n2), A6(n2), T1(n2), T2(n2), U(n2), P(n2), Q(n2);
    mm(M.data(), M.data(), A2.data(), n);
    mm(A2.data(), A2.data(), A4.data(), n);
    mm(A2.data(), A4.data(), A6.data(), n);
    const double b[14] = {64764752532480000.0, 32382376266240000.0, 7771770303897600.0,
                          1187353796428800.0,  129060195264000.0,   10559470521600.0,
                          670442572800.0,      33522128640.0,       1323241920.0,
                          40840800.0,          960960.0,            16380.0,
                          182.0,               1.0};
    for (size_t i = 0; i < n2; ++i) T2[i] = b[13] * A6[i] + b[11] * A4[i] + b[9] * A2[i];
    mm(A6.data(), T2.data(), T1.data(), n);
    for (size_t i = 0; i < n2; ++i) T1[i] += b[7] * A6[i] + b[5] * A4[i] + b[3] * A2[i];
    for (int i = 0; i < n; ++i) T1[(size_t)i * n + i] += b[1];
    mm(M.data(), T1.data(), U.data(), n);
    for (size_t i = 0; i < n2; ++i) T2[i] = b[12] * A6[i] + b[10] * A4[i] + b[8] * A2[i];
    mm(A6.data(), T2.data(), T1.data(), n);
    for (size_t i = 0; i < n2; ++i) T1[i] += b[6] * A6[i] + b[4] * A4[i] + b[2] * A2[i];
    for (int i = 0; i < n; ++i) T1[(size_t)i * n + i] += b[0];
    for (size_t i = 0; i < n2; ++i) { P[i] = T1[i] + U[i]; Q[i] = T1[i] - U[i]; }
    solveMat(Q, P, n);
    for (int r = 0; r < ssq; ++r) { mm(P.data(), P.data(), T1.data(), n); P.swap(T1); }

    std::vector<double> h(MD), hn(MD);
    for (int i = 0; i < MD; ++i) {
      h[i] = P[(size_t)i * n + MD];
      Hmat[i * LL + 0] = (float)h[i];
    }
    for (int t = 1; t < LL; ++t) {
      for (int i = 0; i < MD; ++i) {
        const double* Pi = &P[(size_t)i * n];
        double a = 0;
        for (int k = 0; k < MD; ++k) a += Pi[k] * h[k];
        hn[i] = a;
      }
      for (int i = 0; i < MD; ++i) {
        h[i] = hn[i];
        Hmat[i * LL + t] = (float)hn[i];
      }
    }

    float* p = nullptr;
    if (hipHostMalloc((void**)&p, sizeof(Hmat), hipHostMallocDefault) == hipSuccess
        && p != nullptr) {
      std::memcpy(p, Hmat, sizeof(Hmat));
      Hpinned = p;
    }
  }
};
static HInit g_hinit;

}  // namespace lmu_host

// ============================ device helpers ===============================

__device__ __forceinline__ u16 bf16_hi(float v) {
  u32 u = __float_as_uint(v);
  return (u16)((u + 0x7FFFu + ((u >> 16) & 1u)) >> 16);
}
__device__ __forceinline__ float bf16_tof(u16 h) {
  return __uint_as_float(((u32)h) << 16);
}

// ============================ small kernels ================================

// u[b,l] = relu(sum_d x[b,d,l]*Wu[d] + bu)
__global__ void k_u(const float* __restrict__ x, const float* __restrict__ Wu,
                    const float* __restrict__ bu, float* __restrict__ u) {
  int b = blockIdx.x;
  int t = threadIdx.x;
  int l4 = t & 31, dg = t >> 5;
  const float* xb = x + (size_t)b * DD * LL;
  float4 acc = {0.f, 0.f, 0.f, 0.f};
  for (int d = dg; d < DD; d += 8) {
    float w = Wu[d];
    float4 xv = *reinterpret_cast<const float4*>(xb + (size_t)d * LL + l4 * 4);
    acc.x += w * xv.x; acc.y += w * xv.y; acc.z += w * xv.z; acc.w += w * xv.w;
  }
  __shared__ float4 red[256];
  red[t] = acc;
  __syncthreads();
  if (t < 32) {
    float4 s = red[t];
    for (int g = 1; g < 8; ++g) {
      float4 o = red[g * 32 + t];
      s.x += o.x; s.y += o.y; s.z += o.z; s.w += o.w;
    }
    float bb = bu[0];
    float* up = u + (size_t)b * LL + t * 4;
    up[0] = fmaxf(s.x + bb, 0.f);
    up[1] = fmaxf(s.y + bb, 0.f);
    up[2] = fmaxf(s.z + bb, 0.f);
    up[3] = fmaxf(s.w + bb, 0.f);
  }
}

// G[o,t] = sum_d W_h[o, d] * H[d, t]
__global__ void k_G(const float* __restrict__ Wh, const float* __restrict__ Hm,
                    float* __restrict__ G) {
  int o = blockIdx.x;
  int t = threadIdx.x;  // 128
  const float* wr = Wh + (size_t)o * (2 * DD);
  float a0 = 0.f, a1 = 0.f, a2 = 0.f, a3 = 0.f;
  for (int d = 0; d < DD; d += 4) {
    a0 += wr[d + 0] * Hm[(size_t)(d + 0) * LL + t];
    a1 += wr[d + 1] * Hm[(size_t)(d + 1) * LL + t];
    a2 += wr[d + 2] * Hm[(size_t)(d + 2) * LL + t];
    a3 += wr[d + 3] * Hm[(size_t)(d + 3) * LL + t];
  }
  G[(size_t)o * LL + t] = (a0 + a1) + (a2 + a3);
}

// BN fold: sc = gamma*rsqrt(var+eps); c2 = (cb-mu)*sc + beta
__global__ void k_bn(const float* __restrict__ cb, const float* __restrict__ gam,
                     const float* __restrict__ bet, const float* __restrict__ mu,
                     const float* __restrict__ var, float* __restrict__ sc,
                     float* __restrict__ c2) {
  int i = blockIdx.x * 256 + threadIdx.x;
  if (i < DD) {
    float s = gam[i] * rsqrtf(var[i] + 1e-5f);
    sc[i] = s;
    c2[i] = (cb[i] - mu[i]) * s + bet[i];
  }
}

// A1 = [W_h[:,D:] | G] -> bf16 hi/lo, row-major [768][896]
__global__ void k_splitA1(const float* __restrict__ Wh, const float* __restrict__ G,
                          u16* __restrict__ hi, u16* __restrict__ lo) {
  int i = blockIdx.x * 256 + threadIdx.x;  // 768*896
  if (i >= DD * (DD + LL)) return;
  int o = i / (DD + LL), k = i - o * (DD + LL);
  float v = (k < DD) ? Wh[(size_t)o * (2 * DD) + DD + k]
                     : G[(size_t)o * LL + (k - DD)];
  u16 h = bf16_hi(v);
  hi[i] = h;
  lo[i] = bf16_hi(v - bf16_tof(h));
}

// cw -> bf16 hi/lo, row-major [768][768]
__global__ void k_splitCW(const float* __restrict__ cw, u16* __restrict__ hi,
                          u16* __restrict__ lo) {
  int i = blockIdx.x * 256 + threadIdx.x;  // 768*768
  if (i >= DD * DD) return;
  float v = cw[i];
  u16 h = bf16_hi(v);
  hi[i] = h;
  lo[i] = bf16_hi(v - bf16_tof(h));
}

// ============================ MFMA GEMM ====================================
// C[768 x 128] = A[768 x K] @ B[K x 128] per batch, split-bf16 (3 products).
// MODE 0: A=A1 (K=896; B rows 0..767 = x_b, 768..895 = Toeplitz(u_b));
//         epilogue relu(+bh) -> h.
// MODE 1: A=cw (K=768; B = h_b); epilogue sc*acc + c2 -> out.
// Block: 256 thr = 4 waves (2x2), wave = 64x64 = 4x4 frags of 16x16x32.
// LDS rows padded to 72 bf16 (144 B) -> 2-way read conflicts (free).

#define PK 72

template <int MODE>
__global__ __launch_bounds__(256, 2) void k_gemm(
    const u16* __restrict__ Ahi, const u16* __restrict__ Alo,
    const float* __restrict__ Bsrc, const float* __restrict__ u_base,
    const float* __restrict__ p1, const float* __restrict__ p2,
    float* __restrict__ dst) {
  constexpr int KC = (MODE == 0) ? 14 : 12;   // K-steps of 64
  constexpr int AK = KC * 64;                 // A row stride (896 / 768)
  const int mt = blockIdx.x, by = blockIdx.y;
  const int tid = threadIdx.x, w = tid >> 6, lane = tid & 63;
  const int wm = (w & 1) * 64, wn = (w >> 1) * 64;

  __shared__ u16 Ah_s[128 * PK], Al_s[128 * PK];
  __shared__ u16 Bh_s[128 * PK], Bl_s[128 * PK];
  __shared__ float u_s[LL];

  if (MODE == 0 && tid < LL) u_s[tid] = u_base[(size_t)by * LL + tid];

  const float* Bb = Bsrc + (size_t)by * DD * LL;

  f32x4 acc[4][4];
#pragma unroll
  for (int i = 0; i < 4; ++i)
#pragma unroll
    for (int j = 0; j < 4; ++j) {
      f32x4 z = {0.f, 0.f, 0.f, 0.f};
      acc[i][j] = z;
    }

  // A staging map: thread -> (row = tid>>1, k-half = (tid&1)*32)
  const int ar = tid >> 1, ahalf = tid & 1;
  const u16* AgH = Ahi + (size_t)(mt * 128 + ar) * AK + ahalf * 32;
  const u16* AgL = Alo + (size_t)(mt * 128 + ar) * AK + ahalf * 32;
  // B staging map: thread -> (k0 = 2*(tid>>3), f = tid&7)
  const int k0 = (tid >> 3) * 2, bf_ = tid & 7;

#pragma unroll 1
  for (int kc = 0; kc < KC; ++kc) {
    __syncthreads();
    {  // ---- stage A tile (128 x 64 bf16, hi+lo), padded rows
      const u16* gh = AgH + kc * 64;
      const u16* gl = AgL + kc * 64;
      const int koff0 = ahalf * 32;
#pragma unroll
      for (int c = 0; c < 4; ++c) {
        short8 vh = *(const short8*)(gh + c * 8);
        short8 vl = *(const short8*)(gl + c * 8);
        *(short8*)(&Ah_s[ar * PK + koff0 + c * 8]) = vh;
        *(short8*)(&Al_s[ar * PK + koff0 + c * 8]) = vl;
      }
    }
    {  // ---- stage B tile (64k x 128n) transposed to [n][k], split f32->hi/lo
      const int kg0 = kc * 64 + k0;
#pragma unroll
      for (int g = 0; g < 4; ++g) {
        const int n4 = bf_ * 4 + g * 32;
        float va[4], vb[4];
        if (MODE == 0 && kg0 >= DD) {  // Toeplitz rows from u
          const int tk0 = kg0 - DD, tk1 = tk0 + 1;
#pragma unroll
          for (int e = 0; e < 4; ++e) {
            int n = n4 + e;
            va[e] = (n >= tk0) ? u_s[n - tk0] : 0.f;
            vb[e] = (n >= tk1) ? u_s[n - tk1] : 0.f;
          }
        } else {
          float4 a4 = *(const float4*)(Bb + (size_t)kg0 * LL + n4);
          float4 b4 = *(const float4*)(Bb + (size_t)(kg0 + 1) * LL + n4);
          va[0] = a4.x; va[1] = a4.y; va[2] = a4.z; va[3] = a4.w;
          vb[0] = b4.x; vb[1] = b4.y; vb[2] = b4.z; vb[3] = b4.w;
        }
#pragma unroll
        for (int e = 0; e < 4; ++e) {
          const int n = n4 + e;
          u16 h0 = bf16_hi(va[e]), h1 = bf16_hi(vb[e]);
          u16 l0 = bf16_hi(va[e] - bf16_tof(h0));
          u16 l1 = bf16_hi(vb[e] - bf16_tof(h1));
          *(u32*)(&Bh_s[n * PK + k0]) = (u32)h0 | ((u32)h1 << 16);
          *(u32*)(&Bl_s[n * PK + k0]) = (u32)l0 | ((u32)l1 << 16);
        }
      }
    }
    __syncthreads();
    // ---- compute: 2 kk-steps x 4 mi x 4 ni x 3 split products
#pragma unroll
    for (int kk = 0; kk < 2; ++kk) {
      const int koff = kk * 32 + (lane >> 4) * 8;
      short8 afh[4], afl[4];
#pragma unroll
      for (int mi = 0; mi < 4; ++mi) {
        const int r = wm + mi * 16 + (lane & 15);
        afh[mi] = *(const short8*)(&Ah_s[r * PK + koff]);
        afl[mi] = *(const short8*)(&Al_s[r * PK + koff]);
      }
#pragma unroll
      for (int ni = 0; ni < 4; ++ni) {
        const int n = wn + ni * 16 + (lane & 15);
        short8 bfh = *(const short8*)(&Bh_s[n * PK + koff]);
        short8 bfl = *(const short8*)(&Bl_s[n * PK + koff]);
#pragma unroll
        for (int mi = 0; mi < 4; ++mi) {
          acc[mi][ni] = __builtin_amdgcn_mfma_f32_16x16x32_bf16(afh[mi], bfh, acc[mi][ni], 0, 0, 0);
          acc[mi][ni] = __builtin_amdgcn_mfma_f32_16x16x32_bf16(afh[mi], bfl, acc[mi][ni], 0, 0, 0);
          acc[mi][ni] = __builtin_amdgcn_mfma_f32_16x16x32_bf16(afl[mi], bfh, acc[mi][ni], 0, 0, 0);
        }
      }
    }
  }

  // ---- epilogue: C/D layout col = lane&15, row = (lane>>4)*4 + reg
  const int rb = (lane >> 4) * 4, cN = lane & 15;
#pragma unroll
  for (int mi = 0; mi < 4; ++mi) {
    const int og0 = mt * 128 + wm + mi * 16 + rb;
#pragma unroll
    for (int ni = 0; ni < 4; ++ni) {
      const int l = wn + ni * 16 + cN;
#pragma unroll
      for (int reg = 0; reg < 4; ++reg) {
        const int o = og0 + reg;
        const size_t idx = ((size_t)by * DD + o) * LL + l;
        float v = acc[mi][ni][reg];
        if (MODE == 0) {
          dst[idx] = fmaxf(v + p1[o], 0.f);
        } else {
          dst[idx] = fmaf(p1[o], v, p2[o]);
        }
      }
    }
  }
}

// ============================ launch =======================================

extern "C" void kernel_launch(void* const* d_in, const int* in_sizes, int n_in,
                              void* d_out, int out_size, void* d_ws, size_t ws_size,
                              hipStream_t stream) {
  const float* x   = (const float*)d_in[0];
  const float* Wu  = (const float*)d_in[1];
  const float* bu  = (const float*)d_in[2];
  const float* Wh  = (const float*)d_in[3];
  const float* bh  = (const float*)d_in[4];
  const float* cw  = (const float*)d_in[5];
  const float* cb  = (const float*)d_in[6];
  const float* gam = (const float*)d_in[7];
  const float* bet = (const float*)d_in[8];
  const float* mu  = (const float*)d_in[9];
  const float* var = (const float*)d_in[10];
  float* out = (float*)d_out;

  size_t off = 0;
  auto alloc = [&](size_t bytes) -> void* {
    void* p = (char*)d_ws + off;
    off += (bytes + 255) & ~(size_t)255;
    return p;
  };
  float* H_d  = (float*)alloc(393216);          // 768*128 f32
  float* u_d  = (float*)alloc(131072);          // 256*128 f32
  float* G_d  = (float*)alloc(393216);          // 768*128 f32
  float* sc_d = (float*)alloc(3072);            // 768 f32
  float* c2_d = (float*)alloc(3072);
  u16* A1hi = (u16*)alloc((size_t)DD * 896 * 2);  // 1.38 MB
  u16* A1lo = (u16*)alloc((size_t)DD * 896 * 2);
  u16* cwhi = (u16*)alloc((size_t)DD * DD * 2);   // 1.18 MB
  u16* cwlo = (u16*)alloc((size_t)DD * DD * 2);
  const size_t fixed = off;

  // adaptive batch chunk (ws_size constant per session -> deterministic)
  int nb = 256;
  while (nb > 1 && fixed + (size_t)nb * DD * LL * 4 > ws_size) nb >>= 1;
  float* h_d = (float*)alloc((size_t)nb * DD * LL * 4);

  const float* Hsrc = lmu_host::Hpinned ? lmu_host::Hpinned : lmu_host::Hmat;
  hipMemcpyAsync(H_d, Hsrc, sizeof(lmu_host::Hmat), hipMemcpyHostToDevice, stream);

  hipLaunchKernelGGL(k_u, dim3(256), dim3(256), 0, stream, x, Wu, bu, u_d);
  hipLaunchKernelGGL(k_G, dim3(768), dim3(128), 0, stream, Wh, H_d, G_d);
  hipLaunchKernelGGL(k_bn, dim3(3), dim3(256), 0, stream, cb, gam, bet, mu, var,
                     sc_d, c2_d);
  hipLaunchKernelGGL(k_splitA1, dim3(2688), dim3(256), 0, stream, Wh, G_d, A1hi, A1lo);
  hipLaunchKernelGGL(k_splitCW, dim3(2304), dim3(256), 0, stream, cw, cwhi, cwlo);

  for (int c0 = 0; c0 < BB; c0 += nb) {
    hipLaunchKernelGGL((k_gemm<0>), dim3(6, nb), dim3(256), 0, stream,
                       A1hi, A1lo, x + (size_t)c0 * DD * LL, u_d + (size_t)c0 * LL,
                       bh, (const float*)nullptr, h_d);
    hipLaunchKernelGGL((k_gemm<1>), dim3(6, nb), dim3(256), 0, stream,
                       cwhi, cwlo, h_d, (const float*)nullptr,
                       sc_d, c2_d, out + (size_t)c0 * DD * LL);
  }
}